// Round 10
// baseline (191.325 us; speedup 1.0000x reference)
//
#include <hip/hip_runtime.h>

typedef unsigned char u8;
typedef signed char s8;
typedef unsigned int u32;
typedef __attribute__((ext_vector_type(4))) int i32x4;

#define M_TOK 8192
#define N_OUT 4096
#define K_IN  4096
#define NT    64          // K-tiles of BK=64 int8

// ---------------------------------------------------------------------------
// Fused pre-pass: blocks [0,8192) = per-row absmax quantize x fp32->int8;
// blocks [8192,8704) = unpack int4 (byte-per-int32) -> int8 [O][I]
// ---------------------------------------------------------------------------
static __device__ __forceinline__ u32 pack4(float4 v, float inv) {
    int q0 = __float2int_rn(v.x * inv) & 255;
    int q1 = __float2int_rn(v.y * inv) & 255;
    int q2 = __float2int_rn(v.z * inv) & 255;
    int q3 = __float2int_rn(v.w * inv) & 255;
    return (u32)q0 | ((u32)q1 << 8) | ((u32)q2 << 16) | ((u32)q3 << 24);
}

__global__ __launch_bounds__(256) void prep_kernel(const float* __restrict__ x,
                                                   const int* __restrict__ pw,
                                                   s8* __restrict__ xq,
                                                   float* __restrict__ sx,
                                                   s8* __restrict__ wq) {
    __shared__ float red[4];
    int bid = blockIdx.x;
    int t = threadIdx.x;
    if (bid < M_TOK) {
        int row = bid;
        const float4* xr = (const float4*)(x + (size_t)row * K_IN);
        float4 v0 = xr[t], v1 = xr[t + 256], v2 = xr[t + 512], v3 = xr[t + 768];
        float am = 0.f;
        am = fmaxf(am, fmaxf(fmaxf(fabsf(v0.x), fabsf(v0.y)), fmaxf(fabsf(v0.z), fabsf(v0.w))));
        am = fmaxf(am, fmaxf(fmaxf(fabsf(v1.x), fabsf(v1.y)), fmaxf(fabsf(v1.z), fabsf(v1.w))));
        am = fmaxf(am, fmaxf(fmaxf(fabsf(v2.x), fabsf(v2.y)), fmaxf(fabsf(v2.z), fabsf(v2.w))));
        am = fmaxf(am, fmaxf(fmaxf(fabsf(v3.x), fabsf(v3.y)), fmaxf(fabsf(v3.z), fabsf(v3.w))));
#pragma unroll
        for (int o = 32; o > 0; o >>= 1) am = fmaxf(am, __shfl_xor(am, o));
        if ((t & 63) == 0) red[t >> 6] = am;
        __syncthreads();
        am = fmaxf(fmaxf(red[0], red[1]), fmaxf(red[2], red[3]));
        float inv = (am > 0.f) ? 127.f / am : 0.f;
        if (t == 0) sx[row] = (am > 0.f) ? am / 127.f : 0.f;
        u32* out = (u32*)(xq + (size_t)row * K_IN);
        out[t]       = pack4(v0, inv);
        out[t + 256] = pack4(v1, inv);
        out[t + 512] = pack4(v2, inv);
        out[t + 768] = pack4(v3, inv);
    } else {
        const int n4 = (N_OUT * K_IN / 2) / 4;
        int idx = (bid - M_TOK) * 256 + t;
        const int stride = 512 * 256;
        for (int i = idx; i < n4; i += stride) {
            int4 p = *(const int4*)(pw + (size_t)i * 4);
            u32 lo = (u32)(((p.x & 15) - 8) & 255)
                   | ((u32)((((p.x >> 4) & 15) - 8) & 255) << 8)
                   | ((u32)((((p.y) & 15) - 8) & 255) << 16)
                   | ((u32)((((p.y >> 4) & 15) - 8) & 255) << 24);
            u32 hi = (u32)(((p.z & 15) - 8) & 255)
                   | ((u32)((((p.z >> 4) & 15) - 8) & 255) << 8)
                   | ((u32)((((p.w) & 15) - 8) & 255) << 16)
                   | ((u32)((((p.w >> 4) & 15) - 8) & 255) << 24);
            uint2 o; o.x = lo; o.y = hi;
            *(uint2*)(wq + (size_t)i * 8) = o;
        }
    }
}

// ---------------------------------------------------------------------------
// 128x256 int8 GEMM, BK=64, triple-buffered LDS (72KB -> 2 blocks/CU),
// 1 barrier/tile, counted vmcnt(3) (stage T+2 in flight across boundary).
// C[n][o] = sx[n] * scale[o] * sum_k xq[n][k]*wq[o][k]
// LDS buffer (24KB): [A 128x64 = 8KB][B 256x64 = 16KB], 64B rows,
// read slot swizzle q' = q ^ ((row>>1)&3); staging source inverse-swizzled.
// ---------------------------------------------------------------------------
#define MFMA(a, b, c) __builtin_amdgcn_mfma_i32_16x16x64_i8(a, b, c, 0, 0, 0)

static __device__ __forceinline__ i32x4 ldsv(const u8* p, int idx) {
    return *(const i32x4*)(p + idx);
}

__global__ __launch_bounds__(512, 4) void gemm3b_i8_kernel(const s8* __restrict__ A,
                                                           const s8* __restrict__ B,
                                                           const float* __restrict__ sx,
                                                           const float* __restrict__ scale,
                                                           float* __restrict__ C) {
    __shared__ __align__(16) u8 lds[73728];   // 3 x 24576

#define GLo(src, dstIdx)                                                        \
    __builtin_amdgcn_global_load_lds(                                           \
        (const __attribute__((address_space(1))) void*)(src),                   \
        (__attribute__((address_space(3))) void*)&lds[dstIdx], 16, 0, 0)

    // XCD-aware swizzle: nwg = 1024, divisible by 8
    int wg = blockIdx.x;
    int swz = (wg & 7) * 128 + (wg >> 3);
    int bm = swz >> 4;       // 0..63
    int bn = swz & 15;       // 0..15

    int t = threadIdx.x;
    int l = t & 63;
    int wid = t >> 6;
    int wr = wid >> 2;       // 0..1  (64-row slab of A)
    int wc = wid & 3;        // 0..3  (64-row slab of B)

    // staging: dest byte = t*16 (linear). dest row = t>>2, slot q = t&3.
    // source slot = q ^ ((row>>1)&3)
    const size_t soff = (size_t)(t >> 2) * K_IN + (size_t)((((t & 3) ^ ((t >> 3) & 3)) << 4));
    const size_t S128 = (size_t)128 * K_IN;
    const int t16 = t * 16;

    const s8* Ablk = A + (size_t)(bm * 128) * K_IN;
    const s8* Bblk = B + (size_t)(bn * 256) * K_IN;

    // read addressing: row r at r*64 + (q ^ ((r>>1)&3))*16, q = l>>4
    const int ksw = (((l >> 4) ^ ((l >> 1) & 3)) << 4);
    const int aL = wr * 4096 + (l & 15) * 64 + ksw;          // A region offset
    const int bL = 8192 + wc * 4096 + (l & 15) * 64 + ksw;   // B region offset

    i32x4 acc[4][4] = {};

#define STAGE(DB, TT) do {                                          \
        size_t ko = (size_t)(TT) * 64;                              \
        GLo(Ablk + soff + ko,        (DB) + t16);                   \
        GLo(Bblk + soff + ko,        (DB) + 8192 + t16);            \
        GLo(Bblk + soff + S128 + ko, (DB) + 16384 + t16);           \
    } while (0)

    // ---- prologue: stage tiles 0,1 ----
    STAGE(0, 0);
    STAGE(24576, 1);
    asm volatile("s_waitcnt vmcnt(3)" ::: "memory");   // tile0 complete
    __builtin_amdgcn_s_barrier();

    int cur = 0, stg = 2 * 24576;
    for (int T = 0; T < NT; ++T) {
        const u8* L = lds + cur;

        // stage T+2 into the third buffer (issue-early)
        if (T + 2 < NT) STAGE(stg, T + 2);

        i32x4 b0 = ldsv(L, bL),        b1 = ldsv(L, bL + 1024);
        i32x4 b2 = ldsv(L, bL + 2048), b3 = ldsv(L, bL + 3072);
        i32x4 a0 = ldsv(L, aL),        a1 = ldsv(L, aL + 1024);
        i32x4 a2 = ldsv(L, aL + 2048), a3 = ldsv(L, aL + 3072);

        __builtin_amdgcn_s_setprio(1);
        acc[0][0] = MFMA(a0, b0, acc[0][0]);
        acc[0][1] = MFMA(a0, b1, acc[0][1]);
        acc[0][2] = MFMA(a0, b2, acc[0][2]);
        acc[0][3] = MFMA(a0, b3, acc[0][3]);
        acc[1][0] = MFMA(a1, b0, acc[1][0]);
        acc[1][1] = MFMA(a1, b1, acc[1][1]);
        acc[1][2] = MFMA(a1, b2, acc[1][2]);
        acc[1][3] = MFMA(a1, b3, acc[1][3]);
        acc[2][0] = MFMA(a2, b0, acc[2][0]);
        acc[2][1] = MFMA(a2, b1, acc[2][1]);
        acc[2][2] = MFMA(a2, b2, acc[2][2]);
        acc[2][3] = MFMA(a2, b3, acc[2][3]);
        acc[3][0] = MFMA(a3, b0, acc[3][0]);
        acc[3][1] = MFMA(a3, b1, acc[3][1]);
        acc[3][2] = MFMA(a3, b2, acc[3][2]);
        acc[3][3] = MFMA(a3, b3, acc[3][3]);
        __builtin_amdgcn_s_setprio(0);

        // boundary: drain stage(T+1), keep stage(T+2) in flight
        if (T + 2 < NT)      asm volatile("s_waitcnt vmcnt(3)" ::: "memory");
        else if (T + 1 < NT) asm volatile("s_waitcnt vmcnt(0)" ::: "memory");
        __builtin_amdgcn_s_barrier();

        int nxt = cur + 24576; if (nxt == 73728) nxt = 0;
        cur = nxt;
        stg += 24576; if (stg == 73728) stg = 0;
    }

    // ---- epilogue: C/D layout col = lane&15, row = (lane>>4)*4 + reg ----
    int col0 = bn * 256 + wc * 64 + (l & 15);
    float sc_[4];
#pragma unroll
    for (int n = 0; n < 4; ++n) sc_[n] = scale[col0 + n * 16];

#pragma unroll
    for (int m = 0; m < 4; ++m) {
        int row0 = bm * 128 + wr * 64 + m * 16 + (l >> 4) * 4;
        float4 sxr = *(const float4*)(sx + row0);
        float sxa[4] = {sxr.x, sxr.y, sxr.z, sxr.w};
#pragma unroll
        for (int n = 0; n < 4; ++n) {
            int gcol = col0 + n * 16;
#pragma unroll
            for (int j = 0; j < 4; ++j)
                C[(size_t)(row0 + j) * N_OUT + gcol] = (float)acc[m][n][j] * sxa[j] * sc_[n];
        }
    }
#undef STAGE
#undef GLo
}

// ---------------------------------------------------------------------------
// Fallback (workspace too small): fused fp32 LDS-tiled GEMM
// ---------------------------------------------------------------------------
__global__ __launch_bounds__(256) void gemm_fb_kernel(const float* __restrict__ X,
                                                      const int* __restrict__ PW,
                                                      const float* __restrict__ S,
                                                      float* __restrict__ C) {
    __shared__ float sxm[64][33];
    __shared__ float swm[64][33];
    int bm = blockIdx.x / (N_OUT / 64);
    int bn = blockIdx.x % (N_OUT / 64);
    int t = threadIdx.x;
    int r = t >> 2, c8 = (t & 3) * 8;
    int tx = t & 15, ty = t >> 4;
    float acc[4][4] = {};
    for (int k0 = 0; k0 < K_IN; k0 += 32) {
        const float* xs = X + (size_t)(bm * 64 + r) * K_IN + k0 + c8;
#pragma unroll
        for (int j = 0; j < 8; ++j) sxm[r][c8 + j] = xs[j];
        const int* ps = PW + ((size_t)(bn * 64 + r) * K_IN + k0 + c8) / 2;
#pragma unroll
        for (int j = 0; j < 4; ++j) {
            int b = ps[j];
            swm[r][c8 + 2 * j]     = (float)((b & 15) - 8);
            swm[r][c8 + 2 * j + 1] = (float)(((b >> 4) & 15) - 8);
        }
        __syncthreads();
#pragma unroll
        for (int kk = 0; kk < 32; ++kk) {
            float a[4], w[4];
#pragma unroll
            for (int i = 0; i < 4; ++i) a[i] = sxm[ty * 4 + i][kk];
#pragma unroll
            for (int j = 0; j < 4; ++j) w[j] = swm[tx * 4 + j][kk];
#pragma unroll
            for (int i = 0; i < 4; ++i)
#pragma unroll
                for (int j = 0; j < 4; ++j) acc[i][j] += a[i] * w[j];
        }
        __syncthreads();
    }
#pragma unroll
    for (int i = 0; i < 4; ++i) {
        int gr = bm * 64 + ty * 4 + i;
#pragma unroll
        for (int j = 0; j < 4; ++j) {
            int gc = bn * 64 + tx * 4 + j;
            C[(size_t)gr * N_OUT + gc] = acc[i][j] * S[gc];
        }
    }
}

// ---------------------------------------------------------------------------
// Entry point
// ---------------------------------------------------------------------------
extern "C" void kernel_launch(void* const* d_in, const int* in_sizes, int n_in,
                              void* d_out, int out_size, void* d_ws, size_t ws_size,
                              hipStream_t stream) {
    const float* x  = (const float*)d_in[0];
    const int*   pw = (const int*)d_in[1];
    const float* sc = (const float*)d_in[2];
    float* out = (float*)d_out;

    const size_t xq_bytes = (size_t)M_TOK * K_IN;
    const size_t wq_bytes = (size_t)N_OUT * K_IN;
    const size_t sx_bytes = (size_t)M_TOK * sizeof(float);
    const size_t need = xq_bytes + wq_bytes + sx_bytes;

    if (ws_size >= need) {
        s8* xq = (s8*)d_ws;
        s8* wq = xq + xq_bytes;
        float* sx = (float*)(wq + wq_bytes);
        prep_kernel<<<dim3(M_TOK + 512), dim3(256), 0, stream>>>(x, pw, xq, sx, wq);
        gemm3b_i8_kernel<<<dim3((M_TOK / 128) * (N_OUT / 256)), dim3(512), 0, stream>>>(
            xq, wq, sx, sc, out);
    } else {
        gemm_fb_kernel<<<dim3((M_TOK / 64) * (N_OUT / 64)), dim3(256), 0, stream>>>(x, pw, sc, out);
    }
}